// Round 1
// baseline (343.789 us; speedup 1.0000x reference)
//
#include <hip/hip_runtime.h>

#define NB 4096   // B
#define NS 200    // S
#define NP 8      // P
#define NF 64     // F
#define CHUNKS (NF / 4)   // 16 float4 chunks per 256B item row

__global__ __launch_bounds__(256) void cf_kernel(
    const int*   __restrict__ user,
    const int*   __restrict__ items,
    const float* __restrict__ user_factors,   // [N_USERS][P][F] fp32
    const float* __restrict__ item_factors,   // [N_ITEMS][F]    fp32
    float* __restrict__ out_pred,             // [B][S]          fp32
    float* __restrict__ out_scores)           // [B][S][P]       fp32
{
    __shared__ float u_lds[NF * NP];   // transposed: [f][p], broadcast-read
    __shared__ int   idx_lds[NS];
    __shared__ float v_lds[NS * NF];   // item rows, XOR-swizzled float4 chunks

    const int b   = blockIdx.x;
    const int tid = threadIdx.x;

    // ---- stage user factors (512 fp32, 2KB) into LDS transposed [f][p] ----
    {
        const int uid = user[b];
        const float2* ub = (const float2*)(user_factors + (size_t)uid * (NP * NF));
        float2 w = ub[tid];              // elements 2*tid, 2*tid+1 (p-major)
        int e0 = tid * 2;
        u_lds[(e0 & 63) * NP + (e0 >> 6)] = w.x;
        int e1 = e0 + 1;
        u_lds[(e1 & 63) * NP + (e1 >> 6)] = w.y;
    }
    // ---- stage item indices ----
    if (tid < NS) idx_lds[tid] = items[b * NS + tid];
    __syncthreads();

    // ---- cooperative stage of V: 16 lanes per row, each lane one float4 chunk.
    // One wave instruction covers 4 full rows with contiguous 16-lane segments:
    // every 64B line is consumed by 4 lanes in the SAME instruction (min L1 traffic).
    // XOR swizzle pos = k ^ (row&15): keeps 16B alignment, spreads the per-lane
    // row reads evenly over all 32 banks (8 dword-requests/bank = wave64 floor).
    for (int q = tid; q < NS * CHUNKS; q += 256) {
        int row  = q >> 4;
        int k    = q & 15;
        int gidx = idx_lds[row];
        float4 val = ((const float4*)(item_factors + (size_t)gidx * NF))[k];
        int pos = k ^ (row & 15);
        ((float4*)&v_lds[row * NF])[pos] = val;
    }
    __syncthreads();

    const int s = tid;
    if (s >= NS) return;

    const int sx = s & 15;
    const float4* vrow = (const float4*)&v_lds[s * NF];

    float r[NP];
    #pragma unroll
    for (int p = 0; p < NP; ++p) r[p] = 0.f;

    #pragma unroll
    for (int c = 0; c < NF / 8; ++c) {
        float4 v0 = vrow[(2 * c)     ^ sx];
        float4 v1 = vrow[(2 * c + 1) ^ sx];
        float vf[8] = {v0.x, v0.y, v0.z, v0.w, v1.x, v1.y, v1.z, v1.w};
        #pragma unroll
        for (int j = 0; j < 8; ++j) {
            // wave-uniform LDS address -> broadcast, conflict-free; 2x ds_read_b128
            const float4* up = (const float4*)&u_lds[(c * 8 + j) * NP];
            float4 a  = up[0];
            float4 bb = up[1];
            float vv = vf[j];
            r[0] += vv * a.x;  r[1] += vv * a.y;  r[2] += vv * a.z;  r[3] += vv * a.w;
            r[4] += vv * bb.x; r[5] += vv * bb.y; r[6] += vv * bb.z; r[7] += vv * bb.w;
        }
    }

    // ---- softmax over P personas ----
    float m = r[0];
    #pragma unroll
    for (int p = 1; p < NP; ++p) m = fmaxf(m, r[p]);
    float e[NP];
    float sum = 0.f;
    #pragma unroll
    for (int p = 0; p < NP; ++p) { e[p] = __expf(r[p] - m); sum += e[p]; }
    float inv = 1.f / sum;

    // pred = sum_p score_p * r_p   (== dot(attentive_user, v))
    float sc[NP];
    float pred = 0.f;
    #pragma unroll
    for (int p = 0; p < NP; ++p) {
        sc[p] = e[p] * inv;
        pred += sc[p] * r[p];
    }

    out_pred[b * NS + s] = pred;
    float4* op = (float4*)(out_scores + (size_t)(b * NS + s) * NP);
    op[0] = make_float4(sc[0], sc[1], sc[2], sc[3]);
    op[1] = make_float4(sc[4], sc[5], sc[6], sc[7]);
}

extern "C" void kernel_launch(void* const* d_in, const int* in_sizes, int n_in,
                              void* d_out, int out_size, void* d_ws, size_t ws_size,
                              hipStream_t stream) {
    const int*   user         = (const int*)d_in[0];
    const int*   items        = (const int*)d_in[1];
    const float* user_factors = (const float*)d_in[2];
    const float* item_factors = (const float*)d_in[3];

    float* out_pred   = (float*)d_out;
    float* out_scores = out_pred + (size_t)NB * NS;   // outputs concatenated: pred, scores

    cf_kernel<<<NB, 256, 0, stream>>>(user, items, user_factors, item_factors,
                                      out_pred, out_scores);
}

// Round 2
// 299.168 us; speedup vs baseline: 1.1491x; 1.1491x over previous
//
#include <hip/hip_runtime.h>

#define NB 4096   // B
#define NS 200    // S
#define NP 8      // P
#define NF 64     // F
#define CHUNKS (NF / 4)          // 16 float4 chunks per 256B item row
#define NCHUNK (NS * CHUNKS)     // 3200 chunks per block
#define MAXIT ((NCHUNK + 255) / 256)   // 13 wave-iterations (waves 0,1: 13; waves 2,3: 12)

__global__ __launch_bounds__(256) void cf_kernel(
    const int*   __restrict__ user,
    const int*   __restrict__ items,
    const float* __restrict__ user_factors,   // [N_USERS][P][F] fp32
    const float* __restrict__ item_factors,   // [N_ITEMS][F]    fp32
    float* __restrict__ out_pred,             // [B][S]          fp32
    float* __restrict__ out_scores)           // [B][S][P]       fp32
{
    __shared__ float u_lds[NF * NP];   // transposed [f][p], broadcast-read      (2 KB)
    __shared__ float v_lds[NS * NF];   // item rows, XOR-swizzled chunks         (50 KB)
    // total 52 KB -> 3 blocks/CU (12 waves/CU)

    const int b    = blockIdx.x;
    const int tid  = threadIdx.x;
    const int wave = tid >> 6;
    const int lane = tid & 63;

    // ---- 1) issue user-factor load (float2/lane, coalesced 2KB row) ----
    const int uid = user[b];
    const float2 w = ((const float2*)(user_factors + (size_t)uid * (NP * NF)))[tid];

    // ---- 2) load all item indices into registers (13 independent loads) ----
    int gidx[MAXIT];
    #pragma unroll
    for (int i = 0; i < MAXIT; ++i) {
        int qb = i * 256 + wave * 64;          // wave-uniform chunk base
        if (qb < NCHUNK) {
            int row = (qb + lane) >> 4;        // 16 lanes per item row
            gidx[i] = items[b * NS + row];
        }
    }

    // ---- 3) async gather: global -> LDS, no VGPR round-trip.
    // LDS dest is linear (base + lane*16, required by global_load_lds);
    // the bank swizzle is applied by pre-swizzling the per-lane GLOBAL source:
    // slot k' of row holds chunk k = k' ^ (row&15)  (XOR involution).
    // Each wave instruction covers 4 rows; 4 lanes share each 64B line
    // (min L1 line traffic: 800 line-requests/block vs 3200 for per-lane gather).
    #pragma unroll
    for (int i = 0; i < MAXIT; ++i) {
        int qb = i * 256 + wave * 64;
        if (qb < NCHUNK) {
            int q   = qb + lane;
            int row = q >> 4;
            int kp  = q & 15;
            int k   = kp ^ (row & 15);
            const float* src = item_factors + (size_t)gidx[i] * NF + k * 4;
            __builtin_amdgcn_global_load_lds(
                (const __attribute__((address_space(1))) void*)src,
                (__attribute__((address_space(3))) void*)&v_lds[qb * 4],
                16, 0, 0);
        }
    }

    // ---- 4) stage user factors transposed [f][p] ----
    {
        int e0 = tid * 2;
        u_lds[(e0 & 63) * NP + (e0 >> 6)] = w.x;
        int e1 = e0 + 1;
        u_lds[(e1 & 63) * NP + (e1 >> 6)] = w.y;
    }

    __syncthreads();   // drains vmcnt(0) + lgkmcnt(0): all gathers + u-stage visible

    const int s = tid;
    if (s >= NS) return;

    const int sx = s & 15;
    const float4* vrow = (const float4*)&v_lds[s * NF];

    float r[NP];
    #pragma unroll
    for (int p = 0; p < NP; ++p) r[p] = 0.f;

    #pragma unroll
    for (int c = 0; c < NF / 8; ++c) {
        // swizzled read: slot j^sx holds chunk j. Bank-exact: 8 dword-req/bank.
        float4 v0 = vrow[(2 * c)     ^ sx];
        float4 v1 = vrow[(2 * c + 1) ^ sx];
        float vf[8] = {v0.x, v0.y, v0.z, v0.w, v1.x, v1.y, v1.z, v1.w};
        #pragma unroll
        for (int j = 0; j < 8; ++j) {
            // wave-uniform LDS address -> broadcast, conflict-free; 2x ds_read_b128
            const float4* up = (const float4*)&u_lds[(c * 8 + j) * NP];
            float4 a  = up[0];
            float4 bb = up[1];
            float vv = vf[j];
            r[0] += vv * a.x;  r[1] += vv * a.y;  r[2] += vv * a.z;  r[3] += vv * a.w;
            r[4] += vv * bb.x; r[5] += vv * bb.y; r[6] += vv * bb.z; r[7] += vv * bb.w;
        }
    }

    // ---- softmax over P personas ----
    float m = r[0];
    #pragma unroll
    for (int p = 1; p < NP; ++p) m = fmaxf(m, r[p]);
    float e[NP];
    float sum = 0.f;
    #pragma unroll
    for (int p = 0; p < NP; ++p) { e[p] = __expf(r[p] - m); sum += e[p]; }
    float inv = 1.f / sum;

    // pred = sum_p score_p * r_p   (== dot(attentive_user, v))
    float sc[NP];
    float pred = 0.f;
    #pragma unroll
    for (int p = 0; p < NP; ++p) {
        sc[p] = e[p] * inv;
        pred += sc[p] * r[p];
    }

    out_pred[b * NS + s] = pred;
    float4* op = (float4*)(out_scores + (size_t)(b * NS + s) * NP);
    op[0] = make_float4(sc[0], sc[1], sc[2], sc[3]);
    op[1] = make_float4(sc[4], sc[5], sc[6], sc[7]);
}

extern "C" void kernel_launch(void* const* d_in, const int* in_sizes, int n_in,
                              void* d_out, int out_size, void* d_ws, size_t ws_size,
                              hipStream_t stream) {
    const int*   user         = (const int*)d_in[0];
    const int*   items        = (const int*)d_in[1];
    const float* user_factors = (const float*)d_in[2];
    const float* item_factors = (const float*)d_in[3];

    float* out_pred   = (float*)d_out;
    float* out_scores = out_pred + (size_t)NB * NS;   // outputs concatenated: pred, scores

    cf_kernel<<<NB, 256, 0, stream>>>(user, items, user_factors, item_factors,
                                      out_pred, out_scores);
}